// Round 10
// baseline (313.667 us; speedup 1.0000x reference)
//
#include <hip/hip_runtime.h>

#define EPSF 1e-7f

constexpr int Bn = 4, Cn = 64, Kn = 19;
constexpr int HWn = 512 * 512;

constexpr int SBLK    = 256;               // 4 waves
constexpr int SCHUNKS = 256;               // stats chunks per image
constexpr int SPIX    = HWn / SCHUNKS;     // 1024 pixels per block (256/wave)
constexpr int NSTEP   = 16;                // 16-pixel MFMA k-steps per wave
constexpr int PARTSZ  = 2464;              // 2432 stats + 19 counts + 13 pad

typedef float f32x16_t  __attribute__((ext_vector_type(16)));
typedef short bf16x8_t  __attribute__((ext_vector_type(8)));

// ---------------- Kernel 1: per-(b,k,c) sum / sumsq / count via MFMA ----------------
// R7 lesson: any per-pixel 19-way accumulator select is VALU-bound (compiler
// if-converts the scalar tree -> ~70 VALU/pixel, 38% VALUBusy, 152us).
// Reformulate: sums = onehot(gt) @ x^T  -> v_mfma_f32_32x32x16_bf16.
// A(32x16)=onehot rows k (rows 19..31 never match -> 0), B(16x32)=x cols c.
// A and B are built in-register with the SAME k-slot convention, so the exact
// hardware k-permutation cancels; only C/D layout matters (HW-verified:
// col=lane&31, row=(reg&3)+8*(reg>>2)+4*(lane>>5)).
__global__ __launch_bounds__(SBLK, 3) void k_stats(
    const float* __restrict__ x, const int* __restrict__ gt,
    float* __restrict__ part)
{
    __shared__ float red[2 * Cn * Kn];       // 2432 floats
    __shared__ float credL[32];

    const int tid  = threadIdx.x;
    const int lane = tid & 63;
    const int w    = tid >> 6;               // wave 0..3
    const int g    = lane >> 5;              // k-slot group
    const int row  = lane & 31;              // A row (class) / B col (channel)

    const int b    = blockIdx.x >> 8;
    const int pix0 = (blockIdx.x & 255) * SPIX + w * 256;

    const int*   gtb = gt + (size_t)b * HWn + pix0;
    const float* xr0 = x + (size_t)b * Cn * HWn + (size_t)row        * HWn + pix0;
    const float* xr1 = x + (size_t)b * Cn * HWn + (size_t)(row + 32) * HWn + pix0;

    f32x16_t d0 = (f32x16_t)0.f, d1 = (f32x16_t)0.f;   // sums  c 0-31 / 32-63
    f32x16_t d2 = (f32x16_t)0.f, d3 = (f32x16_t)0.f;   // sumsq c 0-31 / 32-63
    int cnt = 0;

#define PKBF(lo, hi) ((__builtin_bit_cast(unsigned, (hi)) & 0xFFFF0000u) | \
                      (__builtin_bit_cast(unsigned, (lo)) >> 16))

    #pragma unroll 1
    for (int s = 0; s < NSTEP; ++s) {
        const int p = s * 16 + 4 * g;        // this lane's k-slot pixel base
        const int4   La  = *reinterpret_cast<const int4*>(gtb + p);
        const int4   Lb  = *reinterpret_cast<const int4*>(gtb + p + 8);
        const float4 Fa0 = *reinterpret_cast<const float4*>(xr0 + p);
        const float4 Fb0 = *reinterpret_cast<const float4*>(xr0 + p + 8);
        const float4 Fa1 = *reinterpret_cast<const float4*>(xr1 + p);
        const float4 Fb1 = *reinterpret_cast<const float4*>(xr1 + p + 8);

        // A: one-hot bf16 (1.0 = 0x3F80), k-slots (j&3)+8*(j>>2) within group
        const bool e0 = (La.x == row), e1 = (La.y == row);
        const bool e2 = (La.z == row), e3 = (La.w == row);
        const bool e4 = (Lb.x == row), e5 = (Lb.y == row);
        const bool e6 = (Lb.z == row), e7 = (Lb.w == row);
        int4 av;
        av.x = (e0 ? 0x3F80u : 0u) | (e1 ? 0x3F800000u : 0u);
        av.y = (e2 ? 0x3F80u : 0u) | (e3 ? 0x3F800000u : 0u);
        av.z = (e4 ? 0x3F80u : 0u) | (e5 ? 0x3F800000u : 0u);
        av.w = (e6 ? 0x3F80u : 0u) | (e7 ? 0x3F800000u : 0u);
        const bf16x8_t af = __builtin_bit_cast(bf16x8_t, av);
        cnt += (int)e0 + (int)e1 + (int)e2 + (int)e3
             + (int)e4 + (int)e5 + (int)e6 + (int)e7;

        // B: x (and x^2) truncated to bf16, same k-slot order as A
        int4 bv0, bv1, bq0, bq1;
        bv0.x = PKBF(Fa0.x, Fa0.y); bv0.y = PKBF(Fa0.z, Fa0.w);
        bv0.z = PKBF(Fb0.x, Fb0.y); bv0.w = PKBF(Fb0.z, Fb0.w);
        bv1.x = PKBF(Fa1.x, Fa1.y); bv1.y = PKBF(Fa1.z, Fa1.w);
        bv1.z = PKBF(Fb1.x, Fb1.y); bv1.w = PKBF(Fb1.z, Fb1.w);
        bq0.x = PKBF(Fa0.x * Fa0.x, Fa0.y * Fa0.y); bq0.y = PKBF(Fa0.z * Fa0.z, Fa0.w * Fa0.w);
        bq0.z = PKBF(Fb0.x * Fb0.x, Fb0.y * Fb0.y); bq0.w = PKBF(Fb0.z * Fb0.z, Fb0.w * Fb0.w);
        bq1.x = PKBF(Fa1.x * Fa1.x, Fa1.y * Fa1.y); bq1.y = PKBF(Fa1.z * Fa1.z, Fa1.w * Fa1.w);
        bq1.z = PKBF(Fb1.x * Fb1.x, Fb1.y * Fb1.y); bq1.w = PKBF(Fb1.z * Fb1.z, Fb1.w * Fb1.w);

        d0 = __builtin_amdgcn_mfma_f32_32x32x16_bf16(af, __builtin_bit_cast(bf16x8_t, bv0), d0, 0, 0, 0);
        d1 = __builtin_amdgcn_mfma_f32_32x32x16_bf16(af, __builtin_bit_cast(bf16x8_t, bv1), d1, 0, 0, 0);
        d2 = __builtin_amdgcn_mfma_f32_32x32x16_bf16(af, __builtin_bit_cast(bf16x8_t, bq0), d2, 0, 0, 0);
        d3 = __builtin_amdgcn_mfma_f32_32x32x16_bf16(af, __builtin_bit_cast(bf16x8_t, bq1), d3, 0, 0, 0);
    }

    // counts: lane k (g=0) + lane k+32 (g=1) cover all 16 k-slots
    const float cnt_tot = (float)(cnt + __shfl(cnt, (lane & 31) + 32, 64));

    // cross-wave reduce: wave-sequential, non-atomic
    #pragma unroll 1
    for (int ww = 0; ww < 4; ++ww) {
        if (w == ww) {
            #pragma unroll
            for (int r = 0; r < 16; ++r) {
                const int krow = (r & 3) + 8 * (r >> 2) + 4 * g;   // HW C/D row
                if (krow < Kn) {
                    const int i0 = (krow * 2 + 0) * 64;
                    const int i1 = (krow * 2 + 1) * 64;
                    if (ww == 0) {
                        red[i0 + row]      = d0[r];  red[i0 + row + 32] = d1[r];
                        red[i1 + row]      = d2[r];  red[i1 + row + 32] = d3[r];
                    } else {
                        red[i0 + row]      += d0[r]; red[i0 + row + 32] += d1[r];
                        red[i1 + row]      += d2[r]; red[i1 + row + 32] += d3[r];
                    }
                }
            }
            if (lane < Kn) {
                if (ww == 0) credL[lane] = cnt_tot;
                else         credL[lane] += cnt_tot;
            }
        }
        __syncthreads();
    }

    // emit partials: i = stat*1216 + c*19 + k (+ counts as floats)
    float* pb = part + (size_t)blockIdx.x * PARTSZ;
    for (int i = tid; i < 2 * Cn * Kn; i += SBLK) {
        const int stat = i / (Cn * Kn);
        const int rr   = i - stat * (Cn * Kn);
        const int c = rr / Kn, k = rr - c * Kn;
        pb[i] = red[(k * 2 + stat) * 64 + c];
    }
    if (tid < Kn) pb[2 * Cn * Kn + tid] = credL[tid];
}

// ---------------- Kernel 2: mean/std + mixing weights -> AB table ----------------
__global__ __launch_bounds__(1024) void k_tables(
    const float* __restrict__ part, const float* __restrict__ aug,
    float* __restrict__ tabAB)
{
    __shared__ float mean_s[Kn * Cn];   // [k*64 + c]
    __shared__ float std_s [Kn * Cn];
    __shared__ float wrow  [Kn * Kn];   // [t*19 + k]
    __shared__ float wsum  [Kn];
    __shared__ float validf[Kn], cntf[Kn];

    const int b = blockIdx.x, tid = threadIdx.x;
    const float* pbase = part + (size_t)b * SCHUNKS * PARTSZ;

    if (tid < Kn) {                          // counts (stored as exact floats)
        float s = 0.f;
        for (int blk = 0; blk < SCHUNKS; ++blk)
            s += pbase[(size_t)blk * PARTSZ + 2 * Cn * Kn + tid];
        validf[tid] = (s > 0.f) ? 1.f : 0.f;
        cntf[tid]   = (s > 0.f) ? s : 1.f;
    }
    __syncthreads();

    for (int i = tid; i < Cn * Kn; i += 1024) {             // i = c*19 + k
        float s = 0.f, q = 0.f;
        for (int blk = 0; blk < SCHUNKS; ++blk) {
            s += pbase[(size_t)blk * PARTSZ + i];
            q += pbase[(size_t)blk * PARTSZ + Cn * Kn + i];
        }
        const int c = i / Kn, k = i - c * Kn;
        const float cs  = cntf[k];
        const float m   = s / cs;
        const float var = fmaxf(q / cs - m * m, 0.f);
        mean_s[k * Cn + c] = m;
        std_s [k * Cn + c] = sqrtf(var) + EPSF;
    }
    // FIX (R1): Kn*Kn = 361 -> strided loop.
    for (int i = tid; i < Kn * Kn; i += 1024) {
        const int t = i / Kn, k = i - t * Kn;
        wrow[i] = aug[((size_t)b * Kn + t) * Kn + k] * validf[k];
    }
    __syncthreads();
    if (tid < Kn) {
        float s = 0.f;
        for (int k = 0; k < Kn; ++k) s += wrow[tid * Kn + k];
        wsum[tid] = fmaxf(s, EPSF);
    }
    __syncthreads();
    for (int i = tid; i < Kn * Cn; i += 1024) {             // i = t*64 + c
        const int t = i >> 6, c = i & 63;
        const float inv = 1.f / wsum[t];
        float mm = 0.f, ms = 0.f;
        for (int k = 0; k < Kn; ++k) {
            const float wk = wrow[t * Kn + k] * inv;
            mm += wk * mean_s[k * Cn + c];
            ms += wk * std_s [k * Cn + c];
        }
        const float A  = ms / std_s[t * Cn + c];
        const float Bv = mm - mean_s[t * Cn + c] * A;
        const size_t o = ((size_t)b * Cn * Kn + c * Kn + t) * 2;  // [b][c][k][2]
        tabAB[o + 0] = A;
        tabAB[o + 1] = Bv;
    }
}

// ---------------- Kernel 3: out = x*A[gt] + B[gt] ----------------
constexpr int ABLK = 512;                  // 8 waves; 2 blocks/CU
constexpr int ACHUNKS = 128;               // chunks per image
constexpr int APIX = HWn / ACHUNKS;        // 2048 pixels per block

__global__ __launch_bounds__(ABLK, 4) void k_apply(
    const float* __restrict__ x, const int* __restrict__ gt,
    const float* __restrict__ tabAB, float* __restrict__ out)
{
    __shared__ float ABs[Cn * Kn * 2];   // [(c*19 + k)*2 + {A,B}]
    const int tid   = threadIdx.x;
    const int b     = blockIdx.x >> 7;
    const int chunk = blockIdx.x & 127;

    for (int i = tid; i < Cn * Kn * 2; i += ABLK)
        ABs[i] = tabAB[(size_t)b * Cn * Kn * 2 + i];
    __syncthreads();

    const int p0 = chunk * APIX + tid * 4;
    const int4 L = *reinterpret_cast<const int4*>(gt + (size_t)b * HWn + p0);
    const int l0 = min(max(L.x, 0), Kn - 1);
    const int l1 = min(max(L.y, 0), Kn - 1);
    const int l2 = min(max(L.z, 0), Kn - 1);
    const int l3 = min(max(L.w, 0), Kn - 1);

    const float* xp = x   + (size_t)b * Cn * HWn + p0;
    float*       op = out + (size_t)b * Cn * HWn + p0;

    #pragma unroll 8
    for (int c = 0; c < Cn; ++c) {
        const float4 v = *reinterpret_cast<const float4*>(xp + (size_t)c * HWn);
        const int co = c * Kn;
        const float2 ab0 = *reinterpret_cast<const float2*>(&ABs[(co + l0) * 2]);
        const float2 ab1 = *reinterpret_cast<const float2*>(&ABs[(co + l1) * 2]);
        const float2 ab2 = *reinterpret_cast<const float2*>(&ABs[(co + l2) * 2]);
        const float2 ab3 = *reinterpret_cast<const float2*>(&ABs[(co + l3) * 2]);
        float4 o;
        o.x = v.x * ab0.x + ab0.y;
        o.y = v.y * ab1.x + ab1.y;
        o.z = v.z * ab2.x + ab2.y;
        o.w = v.w * ab3.x + ab3.y;
        *reinterpret_cast<float4*>(op + (size_t)c * HWn) = o;
    }
}

extern "C" void kernel_launch(void* const* d_in, const int* in_sizes, int n_in,
                              void* d_out, int out_size, void* d_ws, size_t ws_size,
                              hipStream_t stream) {
    const float* x   = (const float*)d_in[0];
    const int*   gt  = (const int*)d_in[1];
    const float* aug = (const float*)d_in[2];
    float* out = (float*)d_out;

    float* part  = (float*)d_ws;                                  // 1024*2464 = 10.1 MB
    float* tabAB = part + (size_t)Bn * SCHUNKS * PARTSZ;          // 4*64*19*2

    k_stats <<<dim3(Bn * SCHUNKS), dim3(SBLK), 0, stream>>>(x, gt, part);
    k_tables<<<dim3(Bn),           dim3(1024), 0, stream>>>(part, aug, tabAB);
    k_apply <<<dim3(Bn * ACHUNKS), dim3(ABLK), 0, stream>>>(x, gt, tabAB, out);
}

// Round 11
// 239.906 us; speedup vs baseline: 1.3075x; 1.3075x over previous
//
#include <hip/hip_runtime.h>

#define EPSF 1e-7f

constexpr int Bn = 4, Cn = 64, Kn = 19;
constexpr int HWn = 512 * 512;

// k_stats v5 (R11): long-burst staged MFMA.
// R10 lesson: per-lane row-strided reads (1MB power-of-2 stride, 32 lines per
// instruction with identical low address bits) cap effective read BW ~1.8TB/s.
// Fix: stage [32ch x 2048px] tiles with 8KB contiguous bursts per channel row.
constexpr int SCH   = 64;                  // stats chunks per image
constexpr int SPIX  = HWn / SCH;           // 4096 px per block
constexpr int SBLK  = 1024;                // 16 waves
constexpr int HPIX  = 2048;                // px per round
constexpr int TSTR  = 2052;                // tile row stride (bf16); words%32==2 -> 2-way (free)
constexpr int PARTSZ = 2464;               // 2432 stats + 19 counts + pad

typedef float f32x16_t __attribute__((ext_vector_type(16)));
typedef short bf16x8_t __attribute__((ext_vector_type(8)));

#define PKBF(lo, hi) ((__builtin_bit_cast(unsigned, (hi)) & 0xFFFF0000u) | \
                      (__builtin_bit_cast(unsigned, (lo)) >> 16))

__global__ __launch_bounds__(SBLK, 4) void k_stats(
    const float* __restrict__ x, const int* __restrict__ gt,
    float* __restrict__ part)
{
    __shared__ unsigned short tile[32 * TSTR];   // 131,328 B (reused as reduce scratch)
    __shared__ int   lab[SPIX];                  // 16,384 B
    __shared__ float credL[32];

    const int tid  = threadIdx.x;
    const int lane = tid & 63;
    const int w    = tid >> 6;                   // wave 0..15
    const int g    = lane >> 5;                  // k-slot half
    const int col  = lane & 31;                  // MFMA col (channel) / A row (class)

    const int b    = blockIdx.x >> 6;
    const int pix0 = (blockIdx.x & 63) * SPIX;
    const float* xb  = x  + (size_t)b * Cn * HWn + pix0;
    const int*   gtb = gt + (size_t)b * HWn + pix0;

    // stage labels once (clamped)
    {
        const int4 v = *reinterpret_cast<const int4*>(gtb + tid * 4);
        int4 cl;
        cl.x = min(max(v.x, 0), Kn - 1); cl.y = min(max(v.y, 0), Kn - 1);
        cl.z = min(max(v.z, 0), Kn - 1); cl.w = min(max(v.w, 0), Kn - 1);
        *reinterpret_cast<int4*>(&lab[tid * 4]) = cl;
    }

    f32x16_t dS0 = (f32x16_t)0.f, dQ0 = (f32x16_t)0.f;   // channels 0-31
    f32x16_t dS1 = (f32x16_t)0.f, dQ1 = (f32x16_t)0.f;   // channels 32-63
    int cnt = 0;

    // stage: wave w loads channels G*32 + {2w, 2w+1}, 8KB contiguous per row
#define STAGE_(G, H) { \
    _Pragma("unroll") \
    for (int cc = 0; cc < 2; ++cc) { \
        const float* src = xb + (size_t)((G)*32 + w*2 + cc) * HWn + (H) * HPIX; \
        unsigned short* dst = &tile[(w*2 + cc) * TSTR]; \
        _Pragma("unroll") \
        for (int i = 0; i < 8; ++i) { \
            const float4 v = *reinterpret_cast<const float4*>(src + i*256 + lane*4); \
            uint2 pk; pk.x = PKBF(v.x, v.y); pk.y = PKBF(v.z, v.w); \
            *reinterpret_cast<uint2*>(&dst[i*256 + lane*4]) = pk; \
        } \
    } }

    // compute: wave w owns pixels [w*128, w*128+128) of the tile, 8 MFMA steps.
    // A(onehot) and B share the k-slot convention {g-half -> pixels 8g..8g+7},
    // so the HW k-permutation cancels (R10-verified); C/D layout is the only
    // layout dependency: col=lane&31, row=(reg&3)+8*(reg>>2)+4*(lane>>5).
#define COMPUTE_(H, DS, DQ, CNTON) { \
    _Pragma("unroll 1") \
    for (int s = 0; s < 8; ++s) { \
        const int pg = w*128 + s*16 + 8*g; \
        const unsigned short* trow = &tile[col * TSTR + pg]; \
        const uint2 bA = *reinterpret_cast<const uint2*>(trow); \
        const uint2 bB = *reinterpret_cast<const uint2*>(trow + 4); \
        int4 bv; bv.x = (int)bA.x; bv.y = (int)bA.y; bv.z = (int)bB.x; bv.w = (int)bB.y; \
        int4 bq; \
        { \
            const float f0 = __builtin_bit_cast(float, bA.x << 16); \
            const float f1 = __builtin_bit_cast(float, bA.x & 0xFFFF0000u); \
            const float f2 = __builtin_bit_cast(float, bA.y << 16); \
            const float f3 = __builtin_bit_cast(float, bA.y & 0xFFFF0000u); \
            const float f4 = __builtin_bit_cast(float, bB.x << 16); \
            const float f5 = __builtin_bit_cast(float, bB.x & 0xFFFF0000u); \
            const float f6 = __builtin_bit_cast(float, bB.y << 16); \
            const float f7 = __builtin_bit_cast(float, bB.y & 0xFFFF0000u); \
            bq.x = PKBF(f0*f0, f1*f1); bq.y = PKBF(f2*f2, f3*f3); \
            bq.z = PKBF(f4*f4, f5*f5); bq.w = PKBF(f6*f6, f7*f7); \
        } \
        const int4 L0 = *reinterpret_cast<const int4*>(&lab[(H)*HPIX + pg]); \
        const int4 L1 = *reinterpret_cast<const int4*>(&lab[(H)*HPIX + pg + 4]); \
        const bool e0=(L0.x==col), e1=(L0.y==col), e2=(L0.z==col), e3=(L0.w==col); \
        const bool e4=(L1.x==col), e5=(L1.y==col), e6=(L1.z==col), e7=(L1.w==col); \
        int4 av; \
        av.x = (e0?0x3F80u:0u) | (e1?0x3F800000u:0u); \
        av.y = (e2?0x3F80u:0u) | (e3?0x3F800000u:0u); \
        av.z = (e4?0x3F80u:0u) | (e5?0x3F800000u:0u); \
        av.w = (e6?0x3F80u:0u) | (e7?0x3F800000u:0u); \
        if (CNTON) cnt += (int)e0+(int)e1+(int)e2+(int)e3+(int)e4+(int)e5+(int)e6+(int)e7; \
        DS = __builtin_amdgcn_mfma_f32_32x32x16_bf16( \
                 __builtin_bit_cast(bf16x8_t, av), __builtin_bit_cast(bf16x8_t, bv), DS, 0, 0, 0); \
        DQ = __builtin_amdgcn_mfma_f32_32x32x16_bf16( \
                 __builtin_bit_cast(bf16x8_t, av), __builtin_bit_cast(bf16x8_t, bq), DQ, 0, 0, 0); \
    } }

    // 4 rounds: (G=0,h=0) (G=1,h=0) (G=0,h=1) (G=1,h=1); count only on G=0
    STAGE_(0, 0)
    __syncthreads();                 // labels + tile ready
    COMPUTE_(0, dS0, dQ0, true)
    __syncthreads();                 // tile free
    STAGE_(1, 0)
    __syncthreads();
    COMPUTE_(0, dS1, dQ1, false)
    __syncthreads();
    STAGE_(0, 1)
    __syncthreads();
    COMPUTE_(1, dS0, dQ0, true)
    __syncthreads();
    STAGE_(1, 1)
    __syncthreads();
    COMPUTE_(1, dS1, dQ1, false)

    // combine g-halves of counts (valid on lanes < 32)
    const int cnt2 = cnt + __shfl(cnt, col + 32, 64);

    // cross-wave reduce into tile-as-scratch: red[k*128 + stat*64 + ch]
    __syncthreads();
    float* redf = reinterpret_cast<float*>(tile);
    #pragma unroll 1
    for (int ww = 0; ww < 16; ++ww) {
        if (w == ww) {
            #pragma unroll
            for (int r = 0; r < 16; ++r) {
                const int krow = (r & 3) + 8 * (r >> 2) + 4 * g;
                if (krow < Kn) {
                    float* bse = &redf[krow * 128];
                    if (ww == 0) {
                        bse[col]           = dS0[r];  bse[64 + col]      = dQ0[r];
                        bse[32 + col]      = dS1[r];  bse[96 + col]      = dQ1[r];
                    } else {
                        bse[col]          += dS0[r];  bse[64 + col]     += dQ0[r];
                        bse[32 + col]     += dS1[r];  bse[96 + col]     += dQ1[r];
                    }
                }
            }
            if (lane < Kn) {
                if (ww == 0) credL[lane]  = (float)cnt2;
                else         credL[lane] += (float)cnt2;
            }
        }
        __syncthreads();
    }

    // emit partials: i = stat*1216 + c*19 + k  (+ counts as floats)
    float* pb = part + (size_t)blockIdx.x * PARTSZ;
    for (int i = tid; i < 2 * Cn * Kn; i += SBLK) {
        const int stat = i / (Cn * Kn);
        const int rr   = i - stat * (Cn * Kn);
        const int c = rr / Kn, k = rr - c * Kn;
        pb[i] = redf[k * 128 + stat * 64 + c];
    }
    if (tid < Kn) pb[2 * Cn * Kn + tid] = credL[tid];
}

// ---------------- Kernel 2: mean/std + mixing weights -> AB table ----------------
__global__ __launch_bounds__(1024) void k_tables(
    const float* __restrict__ part, const float* __restrict__ aug,
    float* __restrict__ tabAB)
{
    __shared__ float mean_s[Kn * Cn];   // [k*64 + c]
    __shared__ float std_s [Kn * Cn];
    __shared__ float wrow  [Kn * Kn];   // [t*19 + k]
    __shared__ float wsum  [Kn];
    __shared__ float validf[Kn], cntf[Kn];

    const int b = blockIdx.x, tid = threadIdx.x;
    const float* pbase = part + (size_t)b * SCH * PARTSZ;

    if (tid < Kn) {                          // counts (stored as exact floats)
        float s = 0.f;
        for (int blk = 0; blk < SCH; ++blk)
            s += pbase[(size_t)blk * PARTSZ + 2 * Cn * Kn + tid];
        validf[tid] = (s > 0.f) ? 1.f : 0.f;
        cntf[tid]   = (s > 0.f) ? s : 1.f;
    }
    __syncthreads();

    for (int i = tid; i < Cn * Kn; i += 1024) {             // i = c*19 + k
        float s = 0.f, q = 0.f;
        for (int blk = 0; blk < SCH; ++blk) {
            s += pbase[(size_t)blk * PARTSZ + i];
            q += pbase[(size_t)blk * PARTSZ + Cn * Kn + i];
        }
        const int c = i / Kn, k = i - c * Kn;
        const float cs  = cntf[k];
        const float m   = s / cs;
        const float var = fmaxf(q / cs - m * m, 0.f);
        mean_s[k * Cn + c] = m;
        std_s [k * Cn + c] = sqrtf(var) + EPSF;
    }
    // FIX (R1): Kn*Kn = 361 -> strided loop.
    for (int i = tid; i < Kn * Kn; i += 1024) {
        const int t = i / Kn, k = i - t * Kn;
        wrow[i] = aug[((size_t)b * Kn + t) * Kn + k] * validf[k];
    }
    __syncthreads();
    if (tid < Kn) {
        float s = 0.f;
        for (int k = 0; k < Kn; ++k) s += wrow[tid * Kn + k];
        wsum[tid] = fmaxf(s, EPSF);
    }
    __syncthreads();
    for (int i = tid; i < Kn * Cn; i += 1024) {             // i = t*64 + c
        const int t = i >> 6, c = i & 63;
        const float inv = 1.f / wsum[t];
        float mm = 0.f, ms = 0.f;
        for (int k = 0; k < Kn; ++k) {
            const float wk = wrow[t * Kn + k] * inv;
            mm += wk * mean_s[k * Cn + c];
            ms += wk * std_s [k * Cn + c];
        }
        const float A  = ms / std_s[t * Cn + c];
        const float Bv = mm - mean_s[t * Cn + c] * A;
        const size_t o = ((size_t)b * Cn * Kn + c * Kn + t) * 2;  // [b][c][k][2]
        tabAB[o + 0] = A;
        tabAB[o + 1] = Bv;
    }
}

// ---------------- Kernel 3: out = x*A[gt] + B[gt] ----------------
constexpr int ABLK = 512;                  // 8 waves; 2 blocks/CU
constexpr int ACHUNKS = 128;               // chunks per image
constexpr int APIX = HWn / ACHUNKS;        // 2048 pixels per block

__global__ __launch_bounds__(ABLK, 4) void k_apply(
    const float* __restrict__ x, const int* __restrict__ gt,
    const float* __restrict__ tabAB, float* __restrict__ out)
{
    __shared__ float ABs[Cn * Kn * 2];   // [(c*19 + k)*2 + {A,B}]
    const int tid   = threadIdx.x;
    const int b     = blockIdx.x >> 7;
    const int chunk = blockIdx.x & 127;

    for (int i = tid; i < Cn * Kn * 2; i += ABLK)
        ABs[i] = tabAB[(size_t)b * Cn * Kn * 2 + i];
    __syncthreads();

    const int p0 = chunk * APIX + tid * 4;
    const int4 L = *reinterpret_cast<const int4*>(gt + (size_t)b * HWn + p0);
    const int l0 = min(max(L.x, 0), Kn - 1);
    const int l1 = min(max(L.y, 0), Kn - 1);
    const int l2 = min(max(L.z, 0), Kn - 1);
    const int l3 = min(max(L.w, 0), Kn - 1);

    const float* xp = x   + (size_t)b * Cn * HWn + p0;
    float*       op = out + (size_t)b * Cn * HWn + p0;

    #pragma unroll 8
    for (int c = 0; c < Cn; ++c) {
        const float4 v = *reinterpret_cast<const float4*>(xp + (size_t)c * HWn);
        const int co = c * Kn;
        const float2 ab0 = *reinterpret_cast<const float2*>(&ABs[(co + l0) * 2]);
        const float2 ab1 = *reinterpret_cast<const float2*>(&ABs[(co + l1) * 2]);
        const float2 ab2 = *reinterpret_cast<const float2*>(&ABs[(co + l2) * 2]);
        const float2 ab3 = *reinterpret_cast<const float2*>(&ABs[(co + l3) * 2]);
        float4 o;
        o.x = v.x * ab0.x + ab0.y;
        o.y = v.y * ab1.x + ab1.y;
        o.z = v.z * ab2.x + ab2.y;
        o.w = v.w * ab3.x + ab3.y;
        *reinterpret_cast<float4*>(op + (size_t)c * HWn) = o;
    }
}

extern "C" void kernel_launch(void* const* d_in, const int* in_sizes, int n_in,
                              void* d_out, int out_size, void* d_ws, size_t ws_size,
                              hipStream_t stream) {
    const float* x   = (const float*)d_in[0];
    const int*   gt  = (const int*)d_in[1];
    const float* aug = (const float*)d_in[2];
    float* out = (float*)d_out;

    float* part  = (float*)d_ws;                                  // 256*2464 = 2.5 MB
    float* tabAB = part + (size_t)Bn * SCH * PARTSZ;              // 4*64*19*2

    k_stats <<<dim3(Bn * SCH),     dim3(SBLK), 0, stream>>>(x, gt, part);
    k_tables<<<dim3(Bn),           dim3(1024), 0, stream>>>(part, aug, tabAB);
    k_apply <<<dim3(Bn * ACHUNKS), dim3(ABLK), 0, stream>>>(x, gt, tabAB, out);
}

// Round 13
// 170.463 us; speedup vs baseline: 1.8401x; 1.4074x over previous
//
#include <hip/hip_runtime.h>

#define EPSF 1e-7f

constexpr int Bn = 4, Cn = 64, Kn = 19;
constexpr int HWn = 512 * 512;

// k_stats v5 (R11, kept): long-burst staged MFMA. ~85-95us @ ~3.1 TB/s read.
constexpr int SCH   = 64;                  // stats chunks per image
constexpr int SPIX  = HWn / SCH;           // 4096 px per block
constexpr int SBLK  = 1024;                // 16 waves
constexpr int HPIX  = 2048;                // px per round
constexpr int TSTR  = 2052;                // tile row stride (bf16); words%32==2 -> 2-way (free)
constexpr int PARTSZ = 2464;               // 2432 stats + 19 counts + pad

typedef float f32x16_t __attribute__((ext_vector_type(16)));
typedef float f32x4_t  __attribute__((ext_vector_type(4)));
typedef short bf16x8_t __attribute__((ext_vector_type(8)));

#define PKBF(lo, hi) ((__builtin_bit_cast(unsigned, (hi)) & 0xFFFF0000u) | \
                      (__builtin_bit_cast(unsigned, (lo)) >> 16))

__global__ __launch_bounds__(SBLK, 4) void k_stats(
    const float* __restrict__ x, const int* __restrict__ gt,
    float* __restrict__ part)
{
    __shared__ unsigned short tile[32 * TSTR];   // 131,328 B (reused as reduce scratch)
    __shared__ int   lab[SPIX];                  // 16,384 B
    __shared__ float credL[32];

    const int tid  = threadIdx.x;
    const int lane = tid & 63;
    const int w    = tid >> 6;                   // wave 0..15
    const int g    = lane >> 5;                  // k-slot half
    const int col  = lane & 31;                  // MFMA col (channel) / A row (class)

    const int b    = blockIdx.x >> 6;
    const int pix0 = (blockIdx.x & 63) * SPIX;
    const float* xb  = x  + (size_t)b * Cn * HWn + pix0;
    const int*   gtb = gt + (size_t)b * HWn + pix0;

    // stage labels once (clamped)
    {
        const int4 v = *reinterpret_cast<const int4*>(gtb + tid * 4);
        int4 cl;
        cl.x = min(max(v.x, 0), Kn - 1); cl.y = min(max(v.y, 0), Kn - 1);
        cl.z = min(max(v.z, 0), Kn - 1); cl.w = min(max(v.w, 0), Kn - 1);
        *reinterpret_cast<int4*>(&lab[tid * 4]) = cl;
    }

    f32x16_t dS0 = (f32x16_t)0.f, dQ0 = (f32x16_t)0.f;   // channels 0-31
    f32x16_t dS1 = (f32x16_t)0.f, dQ1 = (f32x16_t)0.f;   // channels 32-63
    int cnt = 0;

    // stage: wave w loads channels G*32 + {2w, 2w+1}, 8KB contiguous per row
#define STAGE_(G, H) { \
    _Pragma("unroll") \
    for (int cc = 0; cc < 2; ++cc) { \
        const float* src = xb + (size_t)((G)*32 + w*2 + cc) * HWn + (H) * HPIX; \
        unsigned short* dst = &tile[(w*2 + cc) * TSTR]; \
        _Pragma("unroll") \
        for (int i = 0; i < 8; ++i) { \
            const float4 v = *reinterpret_cast<const float4*>(src + i*256 + lane*4); \
            uint2 pk; pk.x = PKBF(v.x, v.y); pk.y = PKBF(v.z, v.w); \
            *reinterpret_cast<uint2*>(&dst[i*256 + lane*4]) = pk; \
        } \
    } }

    // compute: wave w owns pixels [w*128, w*128+128) of the tile, 8 MFMA steps.
#define COMPUTE_(H, DS, DQ, CNTON) { \
    _Pragma("unroll 1") \
    for (int s = 0; s < 8; ++s) { \
        const int pg = w*128 + s*16 + 8*g; \
        const unsigned short* trow = &tile[col * TSTR + pg]; \
        const uint2 bA = *reinterpret_cast<const uint2*>(trow); \
        const uint2 bB = *reinterpret_cast<const uint2*>(trow + 4); \
        int4 bv; bv.x = (int)bA.x; bv.y = (int)bA.y; bv.z = (int)bB.x; bv.w = (int)bB.y; \
        int4 bq; \
        { \
            const float f0 = __builtin_bit_cast(float, bA.x << 16); \
            const float f1 = __builtin_bit_cast(float, bA.x & 0xFFFF0000u); \
            const float f2 = __builtin_bit_cast(float, bA.y << 16); \
            const float f3 = __builtin_bit_cast(float, bA.y & 0xFFFF0000u); \
            const float f4 = __builtin_bit_cast(float, bB.x << 16); \
            const float f5 = __builtin_bit_cast(float, bB.x & 0xFFFF0000u); \
            const float f6 = __builtin_bit_cast(float, bB.y << 16); \
            const float f7 = __builtin_bit_cast(float, bB.y & 0xFFFF0000u); \
            bq.x = PKBF(f0*f0, f1*f1); bq.y = PKBF(f2*f2, f3*f3); \
            bq.z = PKBF(f4*f4, f5*f5); bq.w = PKBF(f6*f6, f7*f7); \
        } \
        const int4 L0 = *reinterpret_cast<const int4*>(&lab[(H)*HPIX + pg]); \
        const int4 L1 = *reinterpret_cast<const int4*>(&lab[(H)*HPIX + pg + 4]); \
        const bool e0=(L0.x==col), e1=(L0.y==col), e2=(L0.z==col), e3=(L0.w==col); \
        const bool e4=(L1.x==col), e5=(L1.y==col), e6=(L1.z==col), e7=(L1.w==col); \
        int4 av; \
        av.x = (e0?0x3F80u:0u) | (e1?0x3F800000u:0u); \
        av.y = (e2?0x3F80u:0u) | (e3?0x3F800000u:0u); \
        av.z = (e4?0x3F80u:0u) | (e5?0x3F800000u:0u); \
        av.w = (e6?0x3F80u:0u) | (e7?0x3F800000u:0u); \
        if (CNTON) cnt += (int)e0+(int)e1+(int)e2+(int)e3+(int)e4+(int)e5+(int)e6+(int)e7; \
        DS = __builtin_amdgcn_mfma_f32_32x32x16_bf16( \
                 __builtin_bit_cast(bf16x8_t, av), __builtin_bit_cast(bf16x8_t, bv), DS, 0, 0, 0); \
        DQ = __builtin_amdgcn_mfma_f32_32x32x16_bf16( \
                 __builtin_bit_cast(bf16x8_t, av), __builtin_bit_cast(bf16x8_t, bq), DQ, 0, 0, 0); \
    } }

    STAGE_(0, 0)
    __syncthreads();
    COMPUTE_(0, dS0, dQ0, true)
    __syncthreads();
    STAGE_(1, 0)
    __syncthreads();
    COMPUTE_(0, dS1, dQ1, false)
    __syncthreads();
    STAGE_(0, 1)
    __syncthreads();
    COMPUTE_(1, dS0, dQ0, true)
    __syncthreads();
    STAGE_(1, 1)
    __syncthreads();
    COMPUTE_(1, dS1, dQ1, false)

    const int cnt2 = cnt + __shfl(cnt, col + 32, 64);

    __syncthreads();
    float* redf = reinterpret_cast<float*>(tile);
    #pragma unroll 1
    for (int ww = 0; ww < 16; ++ww) {
        if (w == ww) {
            #pragma unroll
            for (int r = 0; r < 16; ++r) {
                const int krow = (r & 3) + 8 * (r >> 2) + 4 * g;
                if (krow < Kn) {
                    float* bse = &redf[krow * 128];
                    if (ww == 0) {
                        bse[col]           = dS0[r];  bse[64 + col]      = dQ0[r];
                        bse[32 + col]      = dS1[r];  bse[96 + col]      = dQ1[r];
                    } else {
                        bse[col]          += dS0[r];  bse[64 + col]     += dQ0[r];
                        bse[32 + col]     += dS1[r];  bse[96 + col]     += dQ1[r];
                    }
                }
            }
            if (lane < Kn) {
                if (ww == 0) credL[lane]  = (float)cnt2;
                else         credL[lane] += (float)cnt2;
            }
        }
        __syncthreads();
    }

    float* pb = part + (size_t)blockIdx.x * PARTSZ;
    for (int i = tid; i < 2 * Cn * Kn; i += SBLK) {
        const int stat = i / (Cn * Kn);
        const int rr   = i - stat * (Cn * Kn);
        const int c = rr / Kn, k = rr - c * Kn;
        pb[i] = redf[k * 128 + stat * 64 + c];
    }
    if (tid < Kn) pb[2 * Cn * Kn + tid] = credL[tid];
}

// ---------------- Kernel 2: mean/std + mixing weights -> AB table ----------------
__global__ __launch_bounds__(1024) void k_tables(
    const float* __restrict__ part, const float* __restrict__ aug,
    float* __restrict__ tabAB)
{
    __shared__ float mean_s[Kn * Cn];   // [k*64 + c]
    __shared__ float std_s [Kn * Cn];
    __shared__ float wrow  [Kn * Kn];   // [t*19 + k]
    __shared__ float wsum  [Kn];
    __shared__ float validf[Kn], cntf[Kn];

    const int b = blockIdx.x, tid = threadIdx.x;
    const float* pbase = part + (size_t)b * SCH * PARTSZ;

    if (tid < Kn) {
        float s = 0.f;
        for (int blk = 0; blk < SCH; ++blk)
            s += pbase[(size_t)blk * PARTSZ + 2 * Cn * Kn + tid];
        validf[tid] = (s > 0.f) ? 1.f : 0.f;
        cntf[tid]   = (s > 0.f) ? s : 1.f;
    }
    __syncthreads();

    for (int i = tid; i < Cn * Kn; i += 1024) {             // i = c*19 + k
        float s = 0.f, q = 0.f;
        for (int blk = 0; blk < SCH; ++blk) {
            s += pbase[(size_t)blk * PARTSZ + i];
            q += pbase[(size_t)blk * PARTSZ + Cn * Kn + i];
        }
        const int c = i / Kn, k = i - c * Kn;
        const float cs  = cntf[k];
        const float m   = s / cs;
        const float var = fmaxf(q / cs - m * m, 0.f);
        mean_s[k * Cn + c] = m;
        std_s [k * Cn + c] = sqrtf(var) + EPSF;
    }
    // FIX (R1): Kn*Kn = 361 -> strided loop.
    for (int i = tid; i < Kn * Kn; i += 1024) {
        const int t = i / Kn, k = i - t * Kn;
        wrow[i] = aug[((size_t)b * Kn + t) * Kn + k] * validf[k];
    }
    __syncthreads();
    if (tid < Kn) {
        float s = 0.f;
        for (int k = 0; k < Kn; ++k) s += wrow[tid * Kn + k];
        wsum[tid] = fmaxf(s, EPSF);
    }
    __syncthreads();
    for (int i = tid; i < Kn * Cn; i += 1024) {             // i = t*64 + c
        const int t = i >> 6, c = i & 63;
        const float inv = 1.f / wsum[t];
        float mm = 0.f, ms = 0.f;
        for (int k = 0; k < Kn; ++k) {
            const float wk = wrow[t * Kn + k] * inv;
            mm += wk * mean_s[k * Cn + c];
            ms += wk * std_s [k * Cn + c];
        }
        const float A  = ms / std_s[t * Cn + c];
        const float Bv = mm - mean_s[t * Cn + c] * A;
        const size_t o = ((size_t)b * Cn * Kn + c * Kn + t) * 2;  // [b][c][k][2]
        tabAB[o + 0] = A;
        tabAB[o + 1] = Bv;
    }
}

// ---------------- Kernel 3: out = x*A[gt] + B[gt] ----------------
// R12: burst length x2 (APIX 2048->4096: 16KB contiguous per channel-row
// visit), same 16 waves/CU (1 block of 1024 thr per CU), NT stores for out.
// (R12 fix: __builtin_nontemporal_store needs a clang ext_vector type, not
// HIP's float4 struct -> bit_cast to f32x4_t.)
constexpr int ABLK = 1024;
constexpr int ACH  = 64;                   // chunks per image
constexpr int APIX = HWn / ACH;            // 4096 pixels per block

__global__ __launch_bounds__(ABLK, 4) void k_apply(
    const float* __restrict__ x, const int* __restrict__ gt,
    const float* __restrict__ tabAB, float* __restrict__ out)
{
    __shared__ float ABs[Cn * Kn * 2];   // [(c*19 + k)*2 + {A,B}]
    const int tid   = threadIdx.x;
    const int b     = blockIdx.x >> 6;
    const int chunk = blockIdx.x & 63;

    for (int i = tid; i < Cn * Kn * 2; i += ABLK)
        ABs[i] = tabAB[(size_t)b * Cn * Kn * 2 + i];
    __syncthreads();

    const int p0 = chunk * APIX + tid * 4;
    const int4 L = *reinterpret_cast<const int4*>(gt + (size_t)b * HWn + p0);
    const int l0 = min(max(L.x, 0), Kn - 1);
    const int l1 = min(max(L.y, 0), Kn - 1);
    const int l2 = min(max(L.z, 0), Kn - 1);
    const int l3 = min(max(L.w, 0), Kn - 1);

    const float* xp = x   + (size_t)b * Cn * HWn + p0;
    float*       op = out + (size_t)b * Cn * HWn + p0;

    #pragma unroll 4
    for (int c = 0; c < Cn; ++c) {
        const float4 v = *reinterpret_cast<const float4*>(xp + (size_t)c * HWn);
        const int co = c * Kn;
        const float2 ab0 = *reinterpret_cast<const float2*>(&ABs[(co + l0) * 2]);
        const float2 ab1 = *reinterpret_cast<const float2*>(&ABs[(co + l1) * 2]);
        const float2 ab2 = *reinterpret_cast<const float2*>(&ABs[(co + l2) * 2]);
        const float2 ab3 = *reinterpret_cast<const float2*>(&ABs[(co + l3) * 2]);
        float4 o;
        o.x = v.x * ab0.x + ab0.y;
        o.y = v.y * ab1.x + ab1.y;
        o.z = v.z * ab2.x + ab2.y;
        o.w = v.w * ab3.x + ab3.y;
        __builtin_nontemporal_store(__builtin_bit_cast(f32x4_t, o),
                                    reinterpret_cast<f32x4_t*>(op + (size_t)c * HWn));
    }
}

extern "C" void kernel_launch(void* const* d_in, const int* in_sizes, int n_in,
                              void* d_out, int out_size, void* d_ws, size_t ws_size,
                              hipStream_t stream) {
    const float* x   = (const float*)d_in[0];
    const int*   gt  = (const int*)d_in[1];
    const float* aug = (const float*)d_in[2];
    float* out = (float*)d_out;

    float* part  = (float*)d_ws;                                  // 256*2464 = 2.5 MB
    float* tabAB = part + (size_t)Bn * SCH * PARTSZ;              // 4*64*19*2

    k_stats <<<dim3(Bn * SCH), dim3(SBLK), 0, stream>>>(x, gt, part);
    k_tables<<<dim3(Bn),       dim3(1024), 0, stream>>>(part, aug, tabAB);
    k_apply <<<dim3(Bn * ACH), dim3(ABLK), 0, stream>>>(x, gt, tabAB, out);
}